// Round 7
// baseline (340.827 us; speedup 1.0000x reference)
//
#include <hip/hip_runtime.h>

#define M_TETS 10240
#define N_NODES 2048
#define MAXPH 400
#define NBLK 40
#define NTHR 256
#define NWAVE 160          // NBLK*NTHR/64
#define OWPW 13            // owned nodes per wave (160*13 >= 2048)
#define SPIN_CAP 1000000

// ws word offsets
#define OFF_VAL   12288    // 3 bufs x 2048 x 4 floats
#define OFF_CNT   36864    // 3 x 2048 u32
#define OFF_DEG   43008    // 2048 u32
#define OFF_DSLOT 45056    // 2 sets x 192 slots x 4 floats

// log(500), log(10000)
__device__ __constant__ float LOG_A_MIN_C = 6.2146080984221914f;
__device__ __constant__ float LOG_A_MAX_C = 9.2103403719761836f;

__device__ __forceinline__ void rel_fence() { __builtin_amdgcn_fence(__ATOMIC_RELEASE, "agent"); }
__device__ __forceinline__ void acq_fence() { __builtin_amdgcn_fence(__ATOMIC_ACQUIRE, "agent"); }
__device__ __forceinline__ unsigned aldu(const unsigned* p) {
    return __hip_atomic_load(p, __ATOMIC_RELAXED, __HIP_MEMORY_SCOPE_AGENT);
}
__device__ __forceinline__ float aldf(const float* p) {
    return __hip_atomic_load(p, __ATOMIC_RELAXED, __HIP_MEMORY_SCOPE_AGENT);
}
__device__ __forceinline__ void astf(float* p, float v) {
    __hip_atomic_store(p, v, __ATOMIC_RELAXED, __HIP_MEMORY_SCOPE_AGENT);
}
__device__ __forceinline__ void astu(unsigned* p, unsigned v) {
    __hip_atomic_store(p, v, __ATOMIC_RELAXED, __HIP_MEMORY_SCOPE_AGENT);
}

__device__ __forceinline__ void bfly3(float& a, float& b, float& c) {
#pragma unroll
    for (int off = 32; off > 0; off >>= 1) {
        a += __shfl_xor(a, off);
        b += __shfl_xor(b, off);
        c += __shfl_xor(c, off);
    }
}

// symmetric 3x3 apply: s6 = [00,01,02,11,12,22]
__device__ __forceinline__ void sym_apply(const float* s6, const float* v, float* out) {
    out[0] = s6[0]*v[0] + s6[1]*v[1] + s6[2]*v[2];
    out[1] = s6[1]*v[0] + s6[3]*v[1] + s6[4]*v[2];
    out[2] = s6[2]*v[0] + s6[4]*v[1] + s6[5]*v[2];
}

__device__ __forceinline__ void sym_inv(const float* s, float* o) {
    float a = s[0], b = s[1], c = s[2], d = s[3], e = s[4], f = s[5];
    float C00 = d*f - e*e, C01 = c*e - b*f, C02 = b*e - c*d;
    float id = 1.0f / (a*C00 + b*C01 + c*C02);
    o[0] = C00*id; o[1] = C01*id; o[2] = C02*id;
    o[3] = (a*f - c*c)*id; o[4] = (b*c - a*e)*id; o[5] = (a*d - b*b)*id;
}

// ---- kernel 1: zero all ws state; init dot-slot tags ----
__global__ void init_kernel(float* ws) {
    const int i = blockIdx.x * blockDim.x + threadIdx.x;
    const int gs = gridDim.x * blockDim.x;
    for (int j = i; j < OFF_DSLOT; j += gs) ws[j] = 0.0f;   // blk6, val, cnt, deg
    float* dslot = ws + OFF_DSLOT;
    for (int j = i; j < 2 * 192; j += gs) {
        float tg = ((j % 192) < NWAVE) ? -1.0f : 1e30f;
        dslot[4*j+0] = 0.f; dslot[4*j+1] = 0.f; dslot[4*j+2] = 0.f; dslot[4*j+3] = tg;
    }
}

// ---- kernel 2: accumulate per-node 3x3 blocks of K and node degrees ----
__global__ void setup_kernel(const float* __restrict__ theta, const float* __restrict__ delta,
                             const float* __restrict__ ra, const float* __restrict__ rs,
                             const float* __restrict__ rv, const float* __restrict__ vol,
                             const int* __restrict__ tets, float* __restrict__ ws) {
    const int e = blockIdx.x * blockDim.x + threadIdx.x;
    if (e >= M_TETS) return;
    float la = theta[0] + delta[e];
    la = fminf(fmaxf(la, LOG_A_MIN_C), LOG_A_MAX_C);
    float al = expf(la);
    float v = vol[e];
    const float cae = v * al, cse = 2.0f * v * al, cve = 8.0f * v * al;
    const int4 t = reinterpret_cast<const int4*>(tets)[e];
    const int nd[4] = {t.x, t.y, t.z, t.w};
    float* blk6 = ws;
    unsigned* deg = (unsigned*)(ws + OFF_DEG);
#pragma unroll
    for (int k = 0; k < 4; k++) {
        float b6[6] = {0,0,0,0,0,0};
#pragma unroll
        for (int a = 0; a < 3; a++) {
            float x0 = ra[e*36 + a*12 + 3*k], x1 = ra[e*36 + a*12 + 3*k+1], x2 = ra[e*36 + a*12 + 3*k+2];
            float s0 = rs[e*36 + a*12 + 3*k], s1 = rs[e*36 + a*12 + 3*k+1], s2 = rs[e*36 + a*12 + 3*k+2];
            b6[0] += cae*x0*x0 + cse*s0*s0;
            b6[1] += cae*x0*x1 + cse*s0*s1;
            b6[2] += cae*x0*x2 + cse*s0*s2;
            b6[3] += cae*x1*x1 + cse*s1*s1;
            b6[4] += cae*x1*x2 + cse*s1*s2;
            b6[5] += cae*x2*x2 + cse*s2*s2;
        }
        float v0 = rv[e*12 + 3*k], v1 = rv[e*12 + 3*k+1], v2 = rv[e*12 + 3*k+2];
        b6[0] += cve*v0*v0; b6[1] += cve*v0*v1; b6[2] += cve*v0*v2;
        b6[3] += cve*v1*v1; b6[4] += cve*v1*v2; b6[5] += cve*v2*v2;
#pragma unroll
        for (int j = 0; j < 6; j++) atomicAdd(&blk6[nd[k]*6 + j], b6[j]);
        atomicAdd(&deg[nd[k]], 1u);
    }
}

// ---- kernel 3: dataflow pipelined PCG (normal launch, 40 blocks co-resident) ----
__global__ void __launch_bounds__(NTHR, 1) pcg_kernel(
    const float* __restrict__ theta, const float* __restrict__ delta,
    const float* __restrict__ ra, const float* __restrict__ rs, const float* __restrict__ rv,
    const float* __restrict__ vol, const float* __restrict__ bvec,
    const int* __restrict__ tets, const int* __restrict__ boundary,
    float* __restrict__ xout, float* __restrict__ ws)
{
    const int tid  = blockIdx.x * blockDim.x + threadIdx.x;  // element id
    const int wid  = tid >> 6;
    const int lane = tid & 63;

    float*    blk6  = ws;
    float*    val   = ws + OFF_VAL;
    unsigned* cnt   = (unsigned*)(ws + OFF_CNT);
    unsigned* deg   = (unsigned*)(ws + OFF_DEG);
    float*    dslot = ws + OFF_DSLOT;

    // ---- element data -> registers ----
    float A[3][12], S[3][12], V[12];
    int nd4[4];
    float cae, cse, cve;
    {
        const int e = tid;
#pragma unroll
        for (int a = 0; a < 3; a++)
#pragma unroll
            for (int i = 0; i < 12; i++) {
                A[a][i] = ra[e * 36 + a * 12 + i];
                S[a][i] = rs[e * 36 + a * 12 + i];
            }
#pragma unroll
        for (int i = 0; i < 12; i++) V[i] = rv[e * 12 + i];
        const int4 t = reinterpret_cast<const int4*>(tets)[e];
        nd4[0] = t.x; nd4[1] = t.y; nd4[2] = t.z; nd4[3] = t.w;
        float la = theta[0] + delta[e];
        la = fminf(fmaxf(la, LOG_A_MIN_C), LOG_A_MAX_C);
        float al = expf(la);
        float v = vol[e];
        cae = v * al; cse = 2.0f * v * al; cve = 8.0f * v * al;
    }

    // ---- per-element: masked B^-1 per node, masks, degrees (kernel boundary = sync) ----
    float ib[4][6], nmask4[4];
    unsigned deg4u[4];
#pragma unroll
    for (int k = 0; k < 4; k++) {
        float bm = boundary[nd4[k]] ? 0.f : 1.f;
        nmask4[k] = bm;
        deg4u[k] = deg[nd4[k]];
        float s6[6];
#pragma unroll
        for (int j = 0; j < 6; j++) s6[j] = blk6[nd4[k]*6 + j];
        float iv[6];
        sym_inv(s6, iv);
#pragma unroll
        for (int j = 0; j < 6; j++) ib[k][j] = iv[j] * bm;
    }

    // ---- owner state (node = wid*13 + lane) ----
    const int own = wid * OWPW + lane;
    const bool ownval = (lane < OWPW) && (own < N_NODES);
    float iO[6] = {0,0,0,0,0,0};
    float maskO = 0.f;
    unsigned degOu = 0;
    float xO[3]={0,0,0}, rO[3]={0,0,0}, uO[3]={0,0,0}, wO[3]={0,0,0}, mO[3]={0,0,0};
    float zO[3]={0,0,0}, qO[3]={0,0,0}, pO[3]={0,0,0}, sO[3]={0,0,0};
    if (ownval) {
        maskO = boundary[own] ? 0.f : 1.f;
        degOu = deg[own];
        float s6[6];
#pragma unroll
        for (int j = 0; j < 6; j++) s6[j] = blk6[own*6 + j];
        float iv[6];
        sym_inv(s6, iv);
#pragma unroll
        for (int j = 0; j < 6; j++) iO[j] = iv[j] * maskO;
#pragma unroll
        for (int j = 0; j < 3; j++) rO[j] = bvec[3*own+j] * maskO;
        sym_apply(iO, rO, uO);
    }

    auto matvec = [&](const float* pe, float* y) {
#pragma unroll
        for (int t = 0; t < 12; t++) y[t] = 0.f;
#pragma unroll
        for (int a = 0; a < 3; a++) {
            float qa = 0.f, qs = 0.f;
#pragma unroll
            for (int t = 0; t < 12; t++) { qa += A[a][t] * pe[t]; qs += S[a][t] * pe[t]; }
            qa *= cae; qs *= cse;
#pragma unroll
            for (int t = 0; t < 12; t++) y[t] += qa * A[a][t] + qs * S[a][t];
        }
        float qv = 0.f;
#pragma unroll
        for (int t = 0; t < 12; t++) qv += V[t] * pe[t];
        qv *= cve;
#pragma unroll
        for (int t = 0; t < 12; t++) y[t] += qv * V[t];
    };

    // ---- phase -1: scatter A*u0 into buf2; release; signal counters ----
    {
        float u0e[12];
#pragma unroll
        for (int k = 0; k < 4; k++) {
            float bb[3] = { bvec[3*nd4[k]], bvec[3*nd4[k]+1], bvec[3*nd4[k]+2] };
            sym_apply(ib[k], bb, &u0e[3*k]);
        }
        float y[12];
        matvec(u0e, y);
        float* v2 = val + 2 * 8192;
#pragma unroll
        for (int kk = 0; kk < 4; kk++)
#pragma unroll
            for (int c = 0; c < 3; c++) atomicAdd(&v2[4*nd4[kk]+c], y[3*kk+c]);
        rel_fence();
        unsigned* c2 = cnt + 2 * N_NODES;
#pragma unroll
        for (int kk = 0; kk < 4; kk++) atomicAdd(&c2[nd4[kk]], 1u);
    }

    // ---- phase 0: consume buf2 (w0); init replicas/owner; scatter A*m0 -> buf0; dots(0) ----
    float w_e[12], z_e[12];
    {
        const unsigned* cR = cnt + 2 * N_NODES;
        int guard = 0;
        for (;;) {
            bool ok = aldu(&cR[nd4[0]]) >= deg4u[0] && aldu(&cR[nd4[1]]) >= deg4u[1]
                   && aldu(&cR[nd4[2]]) >= deg4u[2] && aldu(&cR[nd4[3]]) >= deg4u[3];
            if (ownval) ok = ok && (aldu(&cR[own]) >= degOu);
            if (ok || ++guard > SPIN_CAP) break;
        }
        acq_fence();
        const float* vR = val + 2 * 8192;
#pragma unroll
        for (int kk = 0; kk < 4; kk++) {
            float4 t = *reinterpret_cast<const float4*>(&vR[4*nd4[kk]]);
            w_e[3*kk]   = t.x * nmask4[kk];
            w_e[3*kk+1] = t.y * nmask4[kk];
            w_e[3*kk+2] = t.z * nmask4[kk];
            z_e[3*kk] = 0.f; z_e[3*kk+1] = 0.f; z_e[3*kk+2] = 0.f;
        }
        float me[12];
#pragma unroll
        for (int kk = 0; kk < 4; kk++) sym_apply(ib[kk], &w_e[3*kk], &me[3*kk]);
        float y[12];
        matvec(me, y);
        float* vS = val;   // buf0
#pragma unroll
        for (int kk = 0; kk < 4; kk++)
#pragma unroll
            for (int c = 0; c < 3; c++) atomicAdd(&vS[4*nd4[kk]+c], y[3*kk+c]);

        float gn = 0.f, dn = 0.f, q2 = 0.f;
        if (ownval) {
            float4 t = *reinterpret_cast<const float4*>(&vR[4*own]);
            wO[0] = t.x * maskO; wO[1] = t.y * maskO; wO[2] = t.z * maskO;
            sym_apply(iO, wO, mO);
#pragma unroll
            for (int j = 0; j < 3; j++) {
                gn += rO[j]*uO[j]; dn += wO[j]*uO[j]; q2 += rO[j]*rO[j];
            }
        }
        bfly3(gn, dn, q2);
        float* slot = dslot + (0 * 192 + wid) * 4;   // set 0
        if (lane == 0) { astf(&slot[0], gn); astf(&slot[1], dn); astf(&slot[2], q2); }
        rel_fence();
        unsigned* c0 = cnt;
#pragma unroll
        for (int kk = 0; kk < 4; kk++) atomicAdd(&c0[nd4[kk]], 1u);
        if (lane == 0) astf(&slot[3], 0.0f);
    }

    // ---- main loop: dataflow, no global barriers ----
    float gp = 1.f, ap = 1.f, stop = 0.f;

    for (int k = 1; k <= MAXPH; k++) {
        const int R = (k + 2) % 3, Sb = k % 3, Z = (k + 1) % 3;
        const unsigned* cR = cnt + R * N_NODES;
        const float* vR = val + R * 8192;

        // 1. wait for this element's 4 nodes (+ owned node) of buffer R
        {
            int guard = 0;
            for (;;) {
                bool ok = aldu(&cR[nd4[0]]) >= deg4u[0] && aldu(&cR[nd4[1]]) >= deg4u[1]
                       && aldu(&cR[nd4[2]]) >= deg4u[2] && aldu(&cR[nd4[3]]) >= deg4u[3];
                if (ownval) ok = ok && (aldu(&cR[own]) >= degOu);
                if (ok || ++guard > SPIN_CAP) break;
            }
        }
        acq_fence();

        // 2. gather n (masked)
        float ne[12];
#pragma unroll
        for (int kk = 0; kk < 4; kk++) {
            float4 t = *reinterpret_cast<const float4*>(&vR[4*nd4[kk]]);
            ne[3*kk]   = t.x * nmask4[kk];
            ne[3*kk+1] = t.y * nmask4[kk];
            ne[3*kk+2] = t.z * nmask4[kk];
        }
        float nO[3] = {0,0,0};
        if (ownval) {
            float4 t = *reinterpret_cast<const float4*>(&vR[4*own]);
            nO[0] = t.x * maskO; nO[1] = t.y * maskO; nO[2] = t.z * maskO;
        }

        // 3. dot rendezvous (tags) + reduce
        float gam, del, rho;
        {
            const float* dbase = dslot + ((k - 1) & 1) * 192 * 4;
            const float ttag = (float)(k - 1);
            const int s0 = lane, s1 = lane + 64, s2 = lane + 128;
            int guard = 0;
            for (;;) {
                bool ok = aldf(&dbase[4*s0+3]) >= ttag
                       && aldf(&dbase[4*s1+3]) >= ttag
                       && aldf(&dbase[4*s2+3]) >= ttag;
                if (ok || ++guard > SPIN_CAP) break;
            }
            acq_fence();
            float g  = aldf(&dbase[4*s0])   + aldf(&dbase[4*s1])   + aldf(&dbase[4*s2]);
            float d  = aldf(&dbase[4*s0+1]) + aldf(&dbase[4*s1+1]) + aldf(&dbase[4*s2+1]);
            float r2 = aldf(&dbase[4*s0+2]) + aldf(&dbase[4*s1+2]) + aldf(&dbase[4*s2+2]);
            bfly3(g, d, r2);
            gam = g; del = d; rho = r2;
        }

        if (k == 1) stop = rho * 1e-8f;      // rel residual 1e-4
        else if (rho <= stop) break;         // uniform across grid (same dots everywhere)
        float beta  = (k == 1) ? 0.f : ((gp != 0.f) ? gam / gp : 0.f);
        float den   = (k == 1) ? del : (del - beta * gam / ((ap != 0.f) ? ap : 1.f));
        float alpha = (den != 0.f) ? gam / den : 0.f;

        // 4. element replica update + matvec + value scatter into buffer Sb
        {
#pragma unroll
            for (int t = 0; t < 12; t++) {
                z_e[t] = ne[t] + beta * z_e[t];
                w_e[t] -= alpha * z_e[t];
            }
            float me[12];
#pragma unroll
            for (int kk = 0; kk < 4; kk++) sym_apply(ib[kk], &w_e[3*kk], &me[3*kk]);
            float y[12];
            matvec(me, y);
            float* vS = val + Sb * 8192;
#pragma unroll
            for (int kk = 0; kk < 4; kk++)
#pragma unroll
                for (int c = 0; c < 3; c++) atomicAdd(&vS[4*nd4[kk]+c], y[3*kk+c]);
        }

        // 5. owner recurrences + dot contributions
        float gn = 0.f, dn = 0.f, q2 = 0.f;
        if (ownval) {
#pragma unroll
            for (int j = 0; j < 3; j++) {
                zO[j] = nO[j] + beta * zO[j];
                qO[j] = mO[j] + beta * qO[j];
                pO[j] = uO[j] + beta * pO[j];
                sO[j] = wO[j] + beta * sO[j];
                xO[j] += alpha * pO[j];
                rO[j] -= alpha * sO[j];
                uO[j] -= alpha * qO[j];
                wO[j] -= alpha * zO[j];
            }
            sym_apply(iO, wO, mO);
#pragma unroll
            for (int j = 0; j < 3; j++) {
                gn += rO[j]*uO[j]; dn += wO[j]*uO[j]; q2 += rO[j]*rO[j];
            }
        }
        bfly3(gn, dn, q2);

        // 6. owner zero of buffer Z (values + counter) — all via agent atomics
        if (ownval) {
            float* vZ = val + Z * 8192;
            astf(&vZ[4*own], 0.f); astf(&vZ[4*own+1], 0.f);
            astf(&vZ[4*own+2], 0.f); astf(&vZ[4*own+3], 0.f);
            astu(&cnt[Z * N_NODES + own], 0u);
        }

        // 7. publish dot values; one release fence; then completion signals
        float* slot = dslot + ((k & 1) * 192 + wid) * 4;
        if (lane == 0) { astf(&slot[0], gn); astf(&slot[1], dn); astf(&slot[2], q2); }
        rel_fence();
        {
            unsigned* cS = cnt + Sb * N_NODES;
#pragma unroll
            for (int kk = 0; kk < 4; kk++) atomicAdd(&cS[nd4[kk]], 1u);
        }
        if (lane == 0) astf(&slot[3], (float)k);

        gp = gam; ap = alpha;
    }

    if (ownval) {
#pragma unroll
        for (int j = 0; j < 3; j++) xout[3*own+j] = xO[j];
    }
}

extern "C" void kernel_launch(void* const* d_in, const int* in_sizes, int n_in,
                              void* d_out, int out_size, void* d_ws, size_t ws_size,
                              hipStream_t stream) {
    const float* theta = (const float*)d_in[0];
    const float* delta = (const float*)d_in[1];
    const float* ra    = (const float*)d_in[2];
    const float* rs    = (const float*)d_in[3];
    const float* rv    = (const float*)d_in[4];
    const float* vol   = (const float*)d_in[5];
    const float* b     = (const float*)d_in[6];
    const int* tets    = (const int*)d_in[7];
    const int* boundary = (const int*)d_in[8];
    float* x = (float*)d_out;
    float* ws = (float*)d_ws;

    init_kernel<<<64, 256, 0, stream>>>(ws);
    setup_kernel<<<(M_TETS + 255) / 256, 256, 0, stream>>>(theta, delta, ra, rs, rv, vol, tets, ws);
    pcg_kernel<<<dim3(NBLK), dim3(NTHR), 0, stream>>>(theta, delta, ra, rs, rv, vol, b,
                                                      tets, boundary, x, ws);
}

// Round 8
// 171.290 us; speedup vs baseline: 1.9898x; 1.9898x over previous
//
#include <hip/hip_runtime.h>

#define M_TETS 10240
#define N_NODES 2048
#define MAXPH 400
#define NBLK 32
#define NTHR 320
#define SPIN_CAP 50000000

// ws float offsets
#define OFF_VAL   12288            // blk6: 6*2048 floats at 0
#define OFF_GDOT  36864            // val: 3 bufs x 2048 x 4
#define OFF_SLOT  37248            // gdot: 2 sets x 3 x 64
#define WS_WORDS  37280            // + 32 flag words

// log(500), log(10000)
__device__ __constant__ float LOG_A_MIN_C = 6.2146080984221914f;
__device__ __constant__ float LOG_A_MAX_C = 9.2103403719761836f;

__device__ __forceinline__ void rel_fence() { __builtin_amdgcn_fence(__ATOMIC_RELEASE, "agent"); }
__device__ __forceinline__ void acq_fence() { __builtin_amdgcn_fence(__ATOMIC_ACQUIRE, "agent"); }
__device__ __forceinline__ unsigned aldu(const unsigned* p) {
    return __hip_atomic_load(p, __ATOMIC_RELAXED, __HIP_MEMORY_SCOPE_AGENT);
}
__device__ __forceinline__ float aldf(const float* p) {
    return __hip_atomic_load(p, __ATOMIC_RELAXED, __HIP_MEMORY_SCOPE_AGENT);
}
__device__ __forceinline__ void astf(float* p, float v) {
    __hip_atomic_store(p, v, __ATOMIC_RELAXED, __HIP_MEMORY_SCOPE_AGENT);
}
__device__ __forceinline__ void astu(unsigned* p, unsigned v) {
    __hip_atomic_store(p, v, __ATOMIC_RELAXED, __HIP_MEMORY_SCOPE_AGENT);
}

// Distributed-flag barrier: one publish per block, 32-lane parallel poll.
__device__ __forceinline__ void flag_bar(unsigned* slots, unsigned tgt) {
    rel_fence();
    __syncthreads();
    if (threadIdx.x == 0) astu(&slots[blockIdx.x], tgt);
    if (threadIdx.x < NBLK) {
        int guard = 0;
        while (aldu(&slots[threadIdx.x]) < tgt && ++guard < SPIN_CAP) {}
    }
    __syncthreads();
    acq_fence();
}

__device__ __forceinline__ void bfly3(float& a, float& b, float& c) {
#pragma unroll
    for (int off = 32; off > 0; off >>= 1) {
        a += __shfl_xor(a, off);
        b += __shfl_xor(b, off);
        c += __shfl_xor(c, off);
    }
}

// symmetric 3x3 apply: s6 = [00,01,02,11,12,22]
__device__ __forceinline__ void sym_apply(const float* s6, const float* v, float* out) {
    out[0] = s6[0]*v[0] + s6[1]*v[1] + s6[2]*v[2];
    out[1] = s6[1]*v[0] + s6[3]*v[1] + s6[4]*v[2];
    out[2] = s6[2]*v[0] + s6[4]*v[1] + s6[5]*v[2];
}

__device__ __forceinline__ void sym_inv(const float* s, float* o) {
    float a = s[0], b = s[1], c = s[2], d = s[3], e = s[4], f = s[5];
    float C00 = d*f - e*e, C01 = c*e - b*f, C02 = b*e - c*d;
    float id = 1.0f / (a*C00 + b*C01 + c*C02);
    o[0] = C00*id; o[1] = C01*id; o[2] = C02*id;
    o[3] = (a*f - c*c)*id; o[4] = (b*c - a*e)*id; o[5] = (a*d - b*b)*id;
}

__global__ void __launch_bounds__(NTHR, 1) pcg_kernel(
    const float* __restrict__ theta, const float* __restrict__ delta,
    const float* __restrict__ ra, const float* __restrict__ rs, const float* __restrict__ rv,
    const float* __restrict__ vol, const float* __restrict__ bvec,
    const int* __restrict__ tets, const int* __restrict__ boundary,
    float* __restrict__ xout, float* __restrict__ ws)
{
    const int tid = blockIdx.x * NTHR + threadIdx.x;   // element id, 10240 total
    const int lane = threadIdx.x & 63;
    __shared__ float sd[3];

    float*    blk6  = ws;
    float*    val   = ws + OFF_VAL;
    float*    gdot  = ws + OFF_GDOT;
    unsigned* slots = (unsigned*)(ws + OFF_SLOT);

    // ---- element data -> registers (ws pre-zeroed by hipMemsetAsync) ----
    float A[3][12], S[3][12], V[12];
    int nd4[4];
    float cae, cse, cve;
    {
        const int e = tid;
#pragma unroll
        for (int a = 0; a < 3; a++)
#pragma unroll
            for (int i = 0; i < 12; i++) {
                A[a][i] = ra[e * 36 + a * 12 + i];
                S[a][i] = rs[e * 36 + a * 12 + i];
            }
#pragma unroll
        for (int i = 0; i < 12; i++) V[i] = rv[e * 12 + i];
        const int4 t = reinterpret_cast<const int4*>(tets)[e];
        nd4[0] = t.x; nd4[1] = t.y; nd4[2] = t.z; nd4[3] = t.w;
        float la = theta[0] + delta[e];
        la = fminf(fmaxf(la, LOG_A_MIN_C), LOG_A_MAX_C);
        float al = expf(la);
        float v = vol[e];
        cae = v * al; cse = 2.0f * v * al; cve = 8.0f * v * al;
    }

    auto matvec = [&](const float* pe, float* y) {
#pragma unroll
        for (int t = 0; t < 12; t++) y[t] = 0.f;
#pragma unroll
        for (int a = 0; a < 3; a++) {
            float qa = 0.f, qs = 0.f;
#pragma unroll
            for (int t = 0; t < 12; t++) { qa += A[a][t] * pe[t]; qs += S[a][t] * pe[t]; }
            qa *= cae; qs *= cse;
#pragma unroll
            for (int t = 0; t < 12; t++) y[t] += qa * A[a][t] + qs * S[a][t];
        }
        float qv = 0.f;
#pragma unroll
        for (int t = 0; t < 12; t++) qv += V[t] * pe[t];
        qv *= cve;
#pragma unroll
        for (int t = 0; t < 12; t++) y[t] += qv * V[t];
    };

    // ---- S1: accumulate symmetric per-node 3x3 blocks of K ----
#pragma unroll
    for (int k = 0; k < 4; k++) {
        float b6[6] = {0,0,0,0,0,0};
#pragma unroll
        for (int a = 0; a < 3; a++) {
            float x0 = A[a][3*k], x1 = A[a][3*k+1], x2 = A[a][3*k+2];
            float s0 = S[a][3*k], s1 = S[a][3*k+1], s2 = S[a][3*k+2];
            b6[0] += cae*x0*x0 + cse*s0*s0;
            b6[1] += cae*x0*x1 + cse*s0*s1;
            b6[2] += cae*x0*x2 + cse*s0*s2;
            b6[3] += cae*x1*x1 + cse*s1*s1;
            b6[4] += cae*x1*x2 + cse*s1*s2;
            b6[5] += cae*x2*x2 + cse*s2*s2;
        }
        float v0 = V[3*k], v1 = V[3*k+1], v2 = V[3*k+2];
        b6[0] += cve*v0*v0; b6[1] += cve*v0*v1; b6[2] += cve*v0*v2;
        b6[3] += cve*v1*v1; b6[4] += cve*v1*v2; b6[5] += cve*v2*v2;
#pragma unroll
        for (int j = 0; j < 6; j++) atomicAdd(&blk6[nd4[k]*6 + j], b6[j]);
    }
    flag_bar(slots, 1);

    // ---- local inverses: elements (masked, per node) and owners ----
    float ib[4][6], nmask4[4];
#pragma unroll
    for (int k = 0; k < 4; k++) {
        float bm = boundary[nd4[k]] ? 0.f : 1.f;
        nmask4[k] = bm;
        float s6[6];
#pragma unroll
        for (int j = 0; j < 6; j++) s6[j] = blk6[nd4[k]*6 + j];
        float iv[6];
        sym_inv(s6, iv);
#pragma unroll
        for (int j = 0; j < 6; j++) ib[k][j] = iv[j] * bm;
    }

    const int own = blockIdx.x * 64 + threadIdx.x;   // exact: 32*64 = 2048
    const bool ownval = (threadIdx.x < 64);
    float iO[6] = {0,0,0,0,0,0};
    float maskO = 0.f;
    float xO[3]={0,0,0}, rO[3]={0,0,0}, uO[3]={0,0,0}, wO[3]={0,0,0}, mO[3]={0,0,0};
    float zO[3]={0,0,0}, qO[3]={0,0,0}, pO[3]={0,0,0}, sO[3]={0,0,0};
    if (ownval) {
        maskO = boundary[own] ? 0.f : 1.f;
        float s6[6];
#pragma unroll
        for (int j = 0; j < 6; j++) s6[j] = blk6[own*6 + j];
        float iv[6];
        sym_inv(s6, iv);
#pragma unroll
        for (int j = 0; j < 6; j++) iO[j] = iv[j] * maskO;
#pragma unroll
        for (int j = 0; j < 3; j++) rO[j] = bvec[3*own+j] * maskO;
        sym_apply(iO, rO, uO);
    }

    // ---- phase -1: scatter A*u0 into buf2 ----
    {
        float u0e[12];
#pragma unroll
        for (int k = 0; k < 4; k++) {
            float bb[3] = { bvec[3*nd4[k]], bvec[3*nd4[k]+1], bvec[3*nd4[k]+2] };
            sym_apply(ib[k], bb, &u0e[3*k]);
        }
        float y[12];
        matvec(u0e, y);
        float* v2 = val + 2 * 8192;
#pragma unroll
        for (int kk = 0; kk < 4; kk++)
#pragma unroll
            for (int c = 0; c < 3; c++) atomicAdd(&v2[4*nd4[kk]+c], y[3*kk+c]);
    }
    flag_bar(slots, 2);

    // ---- phase 0: consume buf2 (w0); init replicas/owner; scatter A*m0 -> buf0; dots(0) ----
    float w_e[12], z_e[12];
    {
        const float* vR = val + 2 * 8192;
#pragma unroll
        for (int kk = 0; kk < 4; kk++) {
            float4 t = *reinterpret_cast<const float4*>(&vR[4*nd4[kk]]);
            w_e[3*kk]   = t.x * nmask4[kk];
            w_e[3*kk+1] = t.y * nmask4[kk];
            w_e[3*kk+2] = t.z * nmask4[kk];
            z_e[3*kk] = 0.f; z_e[3*kk+1] = 0.f; z_e[3*kk+2] = 0.f;
        }
        float me[12];
#pragma unroll
        for (int kk = 0; kk < 4; kk++) sym_apply(ib[kk], &w_e[3*kk], &me[3*kk]);
        float y[12];
        matvec(me, y);
        float* vS = val;   // buf0
#pragma unroll
        for (int kk = 0; kk < 4; kk++)
#pragma unroll
            for (int c = 0; c < 3; c++) atomicAdd(&vS[4*nd4[kk]+c], y[3*kk+c]);

        float gn = 0.f, dn = 0.f, q2 = 0.f;
        if (ownval) {
            float4 t = *reinterpret_cast<const float4*>(&vR[4*own]);
            wO[0] = t.x * maskO; wO[1] = t.y * maskO; wO[2] = t.z * maskO;
            sym_apply(iO, wO, mO);
#pragma unroll
            for (int j = 0; j < 3; j++) {
                gn += rO[j]*uO[j]; dn += wO[j]*uO[j]; q2 += rO[j]*rO[j];
            }
            bfly3(gn, dn, q2);
            if (threadIdx.x == 0) {
                astf(&gdot[blockIdx.x], gn);
                astf(&gdot[64 + blockIdx.x], dn);
                astf(&gdot[128 + blockIdx.x], q2);
            }
        }
    }
    flag_bar(slots, 3);

    // ---- main loop: one phase, one barrier per iteration ----
    int rd = 0, sc = 1, ze = 2;
    float gp = 1.f, ap = 1.f, stop = 0.f;
    unsigned tgt = 4;

    for (int k = 1; k <= MAXPH; k++) {
        const float* vR = val + rd * 8192;

        // gather n early (overlaps dot completion)
        float ne[12];
#pragma unroll
        for (int kk = 0; kk < 4; kk++) {
            float4 t = *reinterpret_cast<const float4*>(&vR[4*nd4[kk]]);
            ne[3*kk]   = t.x * nmask4[kk];
            ne[3*kk+1] = t.y * nmask4[kk];
            ne[3*kk+2] = t.z * nmask4[kk];
        }
        float nO[3] = {0,0,0};
        if (ownval) {
            float4 t = *reinterpret_cast<const float4*>(&vR[4*own]);
            nO[0] = t.x * maskO; nO[1] = t.y * maskO; nO[2] = t.z * maskO;
        }

        // cross-block dot completion (wave 0; slots 32..63 are zero-padding)
        if (threadIdx.x < 64) {
            const float* dbase = gdot + ((k - 1) & 1) * 192;
            float g0  = aldf(&dbase[lane]);
            float d0  = aldf(&dbase[64 + lane]);
            float r0c = aldf(&dbase[128 + lane]);
            bfly3(g0, d0, r0c);
            if (threadIdx.x == 0) { sd[0] = g0; sd[1] = d0; sd[2] = r0c; }
        }
        __syncthreads();
        float gam = sd[0], del = sd[1], rho = sd[2];

        if (k == 1) stop = rho * 4e-8f;      // rel residual 2e-4
        else if (rho <= stop) break;         // uniform across grid
        float beta  = (k == 1) ? 0.f : ((gp != 0.f) ? gam / gp : 0.f);
        float den   = (k == 1) ? del : (del - beta * gam / ((ap != 0.f) ? ap : 1.f));
        float alpha = (den != 0.f) ? gam / den : 0.f;

        // element replica update + matvec + scatter into buffer sc
        {
#pragma unroll
            for (int t = 0; t < 12; t++) {
                z_e[t] = ne[t] + beta * z_e[t];
                w_e[t] -= alpha * z_e[t];
            }
            float me[12];
#pragma unroll
            for (int kk = 0; kk < 4; kk++) sym_apply(ib[kk], &w_e[3*kk], &me[3*kk]);
            float y[12];
            matvec(me, y);
            float* vS = val + sc * 8192;
#pragma unroll
            for (int kk = 0; kk < 4; kk++)
#pragma unroll
                for (int c = 0; c < 3; c++) atomicAdd(&vS[4*nd4[kk]+c], y[3*kk+c]);
        }

        // owner recurrences + dot publish + zero buffer ze
        if (ownval) {
            float gn = 0.f, dn = 0.f, q2 = 0.f;
#pragma unroll
            for (int j = 0; j < 3; j++) {
                zO[j] = nO[j] + beta * zO[j];
                qO[j] = mO[j] + beta * qO[j];
                pO[j] = uO[j] + beta * pO[j];
                sO[j] = wO[j] + beta * sO[j];
                xO[j] += alpha * pO[j];
                rO[j] -= alpha * sO[j];
                uO[j] -= alpha * qO[j];
                wO[j] -= alpha * zO[j];
            }
            sym_apply(iO, wO, mO);
#pragma unroll
            for (int j = 0; j < 3; j++) {
                gn += rO[j]*uO[j]; dn += wO[j]*uO[j]; q2 += rO[j]*rO[j];
            }
            bfly3(gn, dn, q2);
            float* gd_pub = gdot + (k & 1) * 192;
            if (threadIdx.x == 0) {
                astf(&gd_pub[blockIdx.x], gn);
                astf(&gd_pub[64 + blockIdx.x], dn);
                astf(&gd_pub[128 + blockIdx.x], q2);
            }
            float* vZ = val + ze * 8192;
            astf(&vZ[4*own+0], 0.f); astf(&vZ[4*own+1], 0.f);
            astf(&vZ[4*own+2], 0.f); astf(&vZ[4*own+3], 0.f);
        }

        gp = gam; ap = alpha;
        flag_bar(slots, tgt++);
        int t2 = rd; rd = sc; sc = ze; ze = t2;
    }

    if (ownval) {
#pragma unroll
        for (int j = 0; j < 3; j++) xout[3*own+j] = xO[j];
    }
}

extern "C" void kernel_launch(void* const* d_in, const int* in_sizes, int n_in,
                              void* d_out, int out_size, void* d_ws, size_t ws_size,
                              hipStream_t stream) {
    const float* theta = (const float*)d_in[0];
    const float* delta = (const float*)d_in[1];
    const float* ra    = (const float*)d_in[2];
    const float* rs    = (const float*)d_in[3];
    const float* rv    = (const float*)d_in[4];
    const float* vol   = (const float*)d_in[5];
    const float* b     = (const float*)d_in[6];
    const int* tets    = (const int*)d_in[7];
    const int* boundary = (const int*)d_in[8];
    float* x = (float*)d_out;
    float* ws = (float*)d_ws;

    hipMemsetAsync(ws, 0, WS_WORDS * sizeof(float), stream);
    pcg_kernel<<<dim3(NBLK), dim3(NTHR), 0, stream>>>(theta, delta, ra, rs, rv, vol, b,
                                                      tets, boundary, x, ws);
}